// Round 3
// baseline (269.756 us; speedup 1.0000x reference)
//
#include <hip/hip_runtime.h>
#include <math.h>

#define NTGT 40000
#define NSRC 40000
#define NEDGE 640000
#define LOG2E 1.44269504088896f

typedef __attribute__((ext_vector_type(8))) short bfrag;   // 8 bf16 in 4 VGPRs
typedef __attribute__((ext_vector_type(4))) short bhalf4;  // 4 bf16 (8B)
typedef __attribute__((ext_vector_type(4))) float f4acc;   // MFMA accumulator

__device__ __forceinline__ ushort f2bf(float f) {
  uint u = __float_as_uint(f);
  u += 0x7fffu + ((u >> 16) & 1u);  // round-to-nearest-even
  return (ushort)(u >> 16);
}
__device__ __forceinline__ float bflo(uint u) { return __uint_as_float(u << 16); }
__device__ __forceinline__ float bfhi(uint u) { return __uint_as_float(u & 0xffff0000u); }
__device__ __forceinline__ float bf2f(short s) { return __uint_as_float(((uint)(ushort)s) << 16); }
__device__ __forceinline__ float sigmoidf_fast(float x) { return 1.0f / (1.0f + __expf(-x)); }

// ---------------- weight prep: transpose + bf16 convert ----------------
__global__ __launch_bounds__(256) void k_wprep(const float* __restrict__ Wq,
                                               const float* __restrict__ Wkv,
                                               const float* __restrict__ Wgt_w,
                                               const float* __restrict__ Wgs_w,
                                               const float* __restrict__ Wo,
                                               short* __restrict__ WqT, short* __restrict__ WkT,
                                               short* __restrict__ WvT, short* __restrict__ WgtT,
                                               short* __restrict__ WgsT, short* __restrict__ WoT) {
  int m = blockIdx.x >> 6;
  int idx = (blockIdx.x & 63) * 256 + threadIdx.x;
  int n = idx >> 7, k = idx & 127;
  const float* src;
  int ld, off;
  short* dst;
  switch (m) {
    case 0: src = Wq;    ld = 128; off = 0;   dst = WqT;  break;
    case 1: src = Wkv;   ld = 256; off = 0;   dst = WkT;  break;
    case 2: src = Wkv;   ld = 256; off = 128; dst = WvT;  break;
    case 3: src = Wgt_w; ld = 128; off = 0;   dst = WgtT; break;
    case 4: src = Wgs_w; ld = 128; off = 0;   dst = WgsT; break;
    default:src = Wo;    ld = 128; off = 0;   dst = WoT;  break;
  }
  dst[n * 128 + k] = (short)f2bf(src[(size_t)k * ld + off + n]);
}

// ---------------- MFMA GEMM building blocks ----------------
__device__ __forceinline__ void stage_rows_f32(const float* __restrict__ X, size_t row0,
                                               short (*Xs)[136], int tid) {
  for (int i = tid; i < 64 * 32; i += 256) {
    int r = i >> 5, c4 = (i & 31) * 4;
    float4 v = *reinterpret_cast<const float4*>(X + (row0 + r) * 128 + c4);
    bhalf4 o;
    o[0] = (short)f2bf(v.x); o[1] = (short)f2bf(v.y);
    o[2] = (short)f2bf(v.z); o[3] = (short)f2bf(v.w);
    *reinterpret_cast<bhalf4*>(&Xs[r][c4]) = o;
  }
}
__device__ __forceinline__ void stage_rows_bf16(const short* __restrict__ X, size_t row0,
                                                short (*Xs)[136], int tid) {
  for (int i = tid; i < 64 * 32; i += 256) {
    int r = i >> 5, c4 = (i & 31) * 4;
    *reinterpret_cast<bhalf4*>(&Xs[r][c4]) =
        *reinterpret_cast<const bhalf4*>(X + (row0 + r) * 128 + c4);
  }
}

__device__ __forceinline__ void mfma_pass(const short (*Xs)[136], int wave, int lane,
                                          const short* __restrict__ WT, f4acc acc[8]) {
  const int rl = wave * 16 + (lane & 15);
  const int kg = (lane >> 4) * 8;
  const int nl = lane & 15;
#pragma unroll
  for (int ks = 0; ks < 4; ++ks) {
    bfrag a = *reinterpret_cast<const bfrag*>(&Xs[rl][ks * 32 + kg]);
#pragma unroll
    for (int nf = 0; nf < 8; ++nf) {
      bfrag b = *reinterpret_cast<const bfrag*>(WT + (size_t)(nf * 16 + nl) * 128 + ks * 32 + kg);
      acc[nf] = __builtin_amdgcn_mfma_f32_16x16x32_bf16(a, b, acc[nf], 0, 0, 0);
    }
  }
}

// ---------------- fused projections (+embedded edge histogram) ----------------
// blocks [0,625): targets -> Qb (pre-scaled), gtb, bt (pre-scaled)
// blocks [625,1250): sources -> KG interleaved (K|GV per dim-pair), bs (pre-scaled)
__global__ __launch_bounds__(256) void k_proj(const float* __restrict__ Xt,
                                              const float* __restrict__ Xsrc,
                                              const short* __restrict__ WqT,
                                              const short* __restrict__ WgtT,
                                              const short* __restrict__ WkT,
                                              const short* __restrict__ WvT,
                                              const short* __restrict__ WgsT,
                                              const float* __restrict__ Wbt,
                                              const float* __restrict__ Wgt_b,
                                              const float* __restrict__ Wbs,
                                              const float* __restrict__ Wgs_b,
                                              const int* __restrict__ inc_tgt,
                                              int* __restrict__ cnt,
                                              short* __restrict__ Qb, short* __restrict__ gtb,
                                              float* __restrict__ bt,
                                              short* __restrict__ KG, float* __restrict__ bs) {
  __shared__ short Xs[64][136];
  const int tid = threadIdx.x;
  // embedded histogram: 512 edges per block, 1250*512 == 640000 exact
  {
    int e0 = blockIdx.x * 512 + tid;
    atomicAdd(&cnt[inc_tgt[e0]], 1);
    atomicAdd(&cnt[inc_tgt[e0 + 256]], 1);
  }
  const bool is_src = blockIdx.x >= 625;
  const int cb = is_src ? blockIdx.x - 625 : blockIdx.x;
  const size_t row0 = (size_t)cb * 64;
  stage_rows_f32(is_src ? Xsrc : Xt, row0, Xs, tid);
  __syncthreads();
  const int wave = tid >> 6, lane = tid & 63;
  const int rbase = (int)row0 + wave * 16 + ((lane >> 4) << 2);
  const int cl = lane & 15;

  if (!is_src) {
    {
      f4acc acc[8] = {};
      mfma_pass(Xs, wave, lane, WqT, acc);
#pragma unroll
      for (int nf = 0; nf < 8; ++nf)
#pragma unroll
        for (int j = 0; j < 4; ++j)
          Qb[(size_t)(rbase + j) * 128 + nf * 16 + cl] =
              (short)f2bf(acc[nf][j] * (0.25f * LOG2E));
    }
    {
      f4acc acc[8] = {};
      mfma_pass(Xs, wave, lane, WgtT, acc);
#pragma unroll
      for (int nf = 0; nf < 8; ++nf)
#pragma unroll
        for (int j = 0; j < 4; ++j) {
          int col = nf * 16 + cl;
          gtb[(size_t)(rbase + j) * 128 + col] =
              (short)f2bf(sigmoidf_fast(acc[nf][j] + Wgt_b[col]));
        }
    }
    for (int o = tid; o < 64 * 8; o += 256) {
      int r = o >> 3, c = o & 7;
      float s = 0.f;
#pragma unroll 4
      for (int k = 0; k < 128; ++k) s = fmaf(bf2f(Xs[r][k]), Wbt[k * 8 + c], s);
      bt[(row0 + r) * 8 + c] = s * LOG2E;
    }
  } else {
    f4acc aK[8] = {};
    f4acc aV[8] = {};
    f4acc aG[8] = {};
    const int rl = wave * 16 + (lane & 15);
    const int kg = (lane >> 4) * 8;
    const int nl = lane & 15;
#pragma unroll
    for (int ks = 0; ks < 4; ++ks) {
      bfrag a = *reinterpret_cast<const bfrag*>(&Xs[rl][ks * 32 + kg]);
#pragma unroll
      for (int nf = 0; nf < 8; ++nf) {
        const size_t wo = (size_t)(nf * 16 + nl) * 128 + ks * 32 + kg;
        bfrag bk = *reinterpret_cast<const bfrag*>(WkT + wo);
        aK[nf] = __builtin_amdgcn_mfma_f32_16x16x32_bf16(a, bk, aK[nf], 0, 0, 0);
        bfrag bv = *reinterpret_cast<const bfrag*>(WvT + wo);
        aV[nf] = __builtin_amdgcn_mfma_f32_16x16x32_bf16(a, bv, aV[nf], 0, 0, 0);
        bfrag bg = *reinterpret_cast<const bfrag*>(WgsT + wo);
        aG[nf] = __builtin_amdgcn_mfma_f32_16x16x32_bf16(a, bg, aG[nf], 0, 0, 0);
      }
    }
#pragma unroll
    for (int nf = 0; nf < 8; ++nf)
#pragma unroll
      for (int j = 0; j < 4; ++j) {
        int col = nf * 16 + cl;
        size_t row = (size_t)(rbase + j);
        float g = sigmoidf_fast(aG[nf][j] + Wgs_b[col]);
        size_t base = row * 256 + (size_t)(col >> 1) * 4 + (col & 1);
        KG[base] = (short)f2bf(aK[nf][j]);
        KG[base + 2] = (short)f2bf(g * aV[nf][j]);
      }
    for (int o = tid; o < 64 * 8; o += 256) {
      int r = o >> 3, c = o & 7;
      float s = 0.f;
#pragma unroll 4
      for (int k = 0; k < 128; ++k) s = fmaf(bf2f(Xs[r][k]), Wbs[k * 8 + c], s);
      bs[(row0 + r) * 8 + c] = s * LOG2E;
    }
  }
}

// ---------------- single-block scan: rowstart = exclusive_prefix(cnt) ----------------
__global__ __launch_bounds__(1024) void k_scan(const int* __restrict__ cnt,
                                               int* __restrict__ rowstart) {
  __shared__ int wsum[16];
  const int tid = threadIdx.x;
  const int base = tid * 40;  // 1024*40 = 40960 >= 40000
  int pref[40];
  int s = 0;
#pragma unroll
  for (int j = 0; j < 40; ++j) {
    int idx = base + j;
    int c = (idx < NTGT) ? cnt[idx] : 0;
    pref[j] = s;
    s += c;
  }
  const int lane = tid & 63, w = tid >> 6;
  int incl = s;
#pragma unroll
  for (int d = 1; d < 64; d <<= 1) {
    int t = __shfl_up(incl, d);
    if (lane >= d) incl += t;
  }
  if (lane == 63) wsum[w] = incl;
  __syncthreads();
  if (tid < 16) {
    int v = wsum[tid];
#pragma unroll
    for (int d = 1; d < 16; d <<= 1) {
      int t = __shfl_up(v, d);
      if (tid >= d) v += t;
    }
    wsum[tid] = v;
  }
  __syncthreads();
  const int tbase = incl - s + (w ? wsum[w - 1] : 0);
#pragma unroll
  for (int j = 0; j < 40; ++j) {
    int idx = base + j;
    if (idx < NTGT) rowstart[idx] = tbase + pref[j];
  }
  if (tid == 1023) rowstart[NTGT] = wsum[15];
}

// ---------------- scatter source index per edge into CSR slots ----------------
__global__ void k_scatter(const int* __restrict__ inc_tgt, const int* __restrict__ inc_src,
                          const int* __restrict__ rowstart, int* __restrict__ cur,
                          int* __restrict__ elist) {
  int e = blockIdx.x * 256 + threadIdx.x;
  if (e < NEDGE) {
    int t = inc_tgt[e];
    int pos = atomicAdd(&cur[t], 1);
    elist[rowstart[t] + pos] = inc_src[e];
  }
}

// ---------------- per-target softmax attention (no max-tracking, exp2 domain) ----------------
__global__ __launch_bounds__(256) void k_attn(const uint* __restrict__ Qp,
                                              const uint2* __restrict__ KGp,
                                              const float* __restrict__ bt,
                                              const float* __restrict__ bs,
                                              const uint* __restrict__ gtp,
                                              const int* __restrict__ rowstart,
                                              const int* __restrict__ elist,
                                              uint* __restrict__ tmpp) {
  const int wave = threadIdx.x >> 6;
  const int lane = threadIdx.x & 63;
  const int t = blockIdx.x * 4 + wave;  // 10000*4 == 40000
  const int h = lane >> 3;

  uint qu = Qp[(size_t)t * 64 + lane];       // pre-scaled by 0.25*log2e
  float qx = bflo(qu), qy = bfhi(qu);
  const float bt2 = bt[(size_t)t * 8 + h];   // pre-scaled by log2e
  const int rs = rowstart[t], re = rowstart[t + 1];

  float ssum = 0.f, a0 = 0.f, a1 = 0.f;
  int i = rs;
  for (; i + 4 <= re; i += 4) {
    int s0 = elist[i], s1 = elist[i + 1], s2 = elist[i + 2], s3 = elist[i + 3];
    uint2 k0 = KGp[(size_t)s0 * 64 + lane];
    uint2 k1 = KGp[(size_t)s1 * 64 + lane];
    uint2 k2 = KGp[(size_t)s2 * 64 + lane];
    uint2 k3 = KGp[(size_t)s3 * 64 + lane];
    float b0 = bs[(size_t)s0 * 8 + h];
    float b1 = bs[(size_t)s1 * 8 + h];
    float b2 = bs[(size_t)s2 * 8 + h];
    float b3 = bs[(size_t)s3 * 8 + h];
    float d0 = qx * bflo(k0.x) + qy * bfhi(k0.x);
    float d1 = qx * bflo(k1.x) + qy * bfhi(k1.x);
    float d2 = qx * bflo(k2.x) + qy * bfhi(k2.x);
    float d3 = qx * bflo(k3.x) + qy * bfhi(k3.x);
    d0 += __shfl_xor(d0, 1); d1 += __shfl_xor(d1, 1); d2 += __shfl_xor(d2, 1); d3 += __shfl_xor(d3, 1);
    d0 += __shfl_xor(d0, 2); d1 += __shfl_xor(d1, 2); d2 += __shfl_xor(d2, 2); d3 += __shfl_xor(d3, 2);
    d0 += __shfl_xor(d0, 4); d1 += __shfl_xor(d1, 4); d2 += __shfl_xor(d2, 4); d3 += __shfl_xor(d3, 4);
    float e0 = __builtin_amdgcn_exp2f(d0 + bt2 + b0);
    float e1 = __builtin_amdgcn_exp2f(d1 + bt2 + b1);
    float e2 = __builtin_amdgcn_exp2f(d2 + bt2 + b2);
    float e3 = __builtin_amdgcn_exp2f(d3 + bt2 + b3);
    ssum += (e0 + e1) + (e2 + e3);
    a0 = fmaf(e0, bflo(k0.y), fmaf(e1, bflo(k1.y), fmaf(e2, bflo(k2.y), fmaf(e3, bflo(k3.y), a0))));
    a1 = fmaf(e0, bfhi(k0.y), fmaf(e1, bfhi(k1.y), fmaf(e2, bfhi(k2.y), fmaf(e3, bfhi(k3.y), a1))));
  }
  for (; i < re; ++i) {
    int s0 = elist[i];
    uint2 k0 = KGp[(size_t)s0 * 64 + lane];
    float b0 = bs[(size_t)s0 * 8 + h];
    float d0 = qx * bflo(k0.x) + qy * bfhi(k0.x);
    d0 += __shfl_xor(d0, 1);
    d0 += __shfl_xor(d0, 2);
    d0 += __shfl_xor(d0, 4);
    float e0 = __builtin_amdgcn_exp2f(d0 + bt2 + b0);
    ssum += e0;
    a0 = fmaf(e0, bflo(k0.y), a0);
    a1 = fmaf(e0, bfhi(k0.y), a1);
  }
  float inv = 1.f / (ssum + 1e-12f);
  uint g2 = gtp[(size_t)t * 64 + lane];
  float ox = bflo(g2) * a0 * inv;
  float oy = bfhi(g2) * a1 * inv;
  tmpp[(size_t)t * 64 + lane] = ((uint)f2bf(ox)) | (((uint)f2bf(oy)) << 16);
}

// ---------------- final GEMM: out = tmp @ Wo (fp32 out) ----------------
__global__ __launch_bounds__(256) void k_out(const short* __restrict__ tmpb,
                                             const short* __restrict__ WoT,
                                             float* __restrict__ out) {
  __shared__ short Xs[64][136];
  const int tid = threadIdx.x;
  const size_t row0 = (size_t)blockIdx.x * 64;
  stage_rows_bf16(tmpb, row0, Xs, tid);
  __syncthreads();
  const int wave = tid >> 6, lane = tid & 63;
  const int rbase = (int)row0 + wave * 16 + ((lane >> 4) << 2);
  const int cl = lane & 15;
  f4acc acc[8] = {};
  mfma_pass(Xs, wave, lane, WoT, acc);
#pragma unroll
  for (int nf = 0; nf < 8; ++nf)
#pragma unroll
    for (int j = 0; j < 4; ++j)
      out[(size_t)(rbase + j) * 128 + nf * 16 + cl] = acc[nf][j];
}

extern "C" void kernel_launch(void* const* d_in, const int* in_sizes, int n_in,
                              void* d_out, int out_size, void* d_ws, size_t ws_size,
                              hipStream_t stream) {
  const float* X_tgt = (const float*)d_in[0];
  const float* X_src = (const float*)d_in[1];
  const int* inc_tgt = (const int*)d_in[2];
  const int* inc_src = (const int*)d_in[3];
  const float* Wq    = (const float*)d_in[5];
  const float* Wkv   = (const float*)d_in[6];
  const float* Wbt   = (const float*)d_in[7];
  const float* Wbs   = (const float*)d_in[8];
  const float* Wgt_w = (const float*)d_in[9];
  const float* Wgt_b = (const float*)d_in[10];
  const float* Wgs_w = (const float*)d_in[11];
  const float* Wgs_b = (const float*)d_in[12];
  const float* Wo    = (const float*)d_in[13];
  float* out = (float*)d_out;

  char* ws = (char*)d_ws;
  short* Qb   = (short*)ws; ws += (size_t)NTGT * 128 * 2;
  short* KG   = (short*)ws; ws += (size_t)NSRC * 256 * 2;
  short* gtb  = (short*)ws; ws += (size_t)NTGT * 128 * 2;
  short* tmpb = (short*)ws; ws += (size_t)NTGT * 128 * 2;
  float* bt   = (float*)ws; ws += (size_t)NTGT * 8 * 4;
  float* bs   = (float*)ws; ws += (size_t)NSRC * 8 * 4;
  int* rowstart = (int*)ws; ws += (size_t)(NTGT + 4) * 4;
  int* cnt  = (int*)ws; ws += (size_t)NTGT * 4;   // cnt & cur adjacent: one memset
  int* cur  = (int*)ws; ws += (size_t)NTGT * 4;
  int* elist = (int*)ws; ws += (size_t)NEDGE * 4;
  short* WqT  = (short*)ws; ws += 128 * 128 * 2;
  short* WkT  = (short*)ws; ws += 128 * 128 * 2;
  short* WvT  = (short*)ws; ws += 128 * 128 * 2;
  short* WgtT = (short*)ws; ws += 128 * 128 * 2;
  short* WgsT = (short*)ws; ws += 128 * 128 * 2;
  short* WoT  = (short*)ws; ws += 128 * 128 * 2;

  hipMemsetAsync(cnt, 0, (size_t)2 * NTGT * 4, stream);

  k_wprep<<<6 * 64, 256, 0, stream>>>(Wq, Wkv, Wgt_w, Wgs_w, Wo, WqT, WkT, WvT, WgtT, WgsT, WoT);
  k_proj<<<1250, 256, 0, stream>>>(X_tgt, X_src, WqT, WgtT, WkT, WvT, WgsT,
                                   Wbt, Wgt_b, Wbs, Wgs_b, inc_tgt, cnt,
                                   Qb, gtb, bt, KG, bs);
  k_scan<<<1, 1024, 0, stream>>>(cnt, rowstart);
  k_scatter<<<NEDGE / 256, 256, 0, stream>>>(inc_tgt, inc_src, rowstart, cur, elist);
  k_attn<<<NTGT / 4, 256, 0, stream>>>((const uint*)Qb, (const uint2*)KG, bt, bs,
                                       (const uint*)gtb, rowstart, elist, (uint*)tmpb);
  k_out<<<NTGT / 64, 256, 0, stream>>>(tmpb, WoT, out);
}

// Round 4
// 261.042 us; speedup vs baseline: 1.0334x; 1.0334x over previous
//
#include <hip/hip_runtime.h>
#include <math.h>

#define NTGT 40000
#define NSRC 40000
#define NEDGE 640000
#define LOG2E 1.44269504088896f
#define KGS 272  // shorts per KG row: 256 K/GV interleaved + 8 bs(bf16) + 8 pad

typedef __attribute__((ext_vector_type(8))) short bfrag;   // 8 bf16 (4 VGPRs)
typedef __attribute__((ext_vector_type(4))) short bhalf4;  // 8B
typedef __attribute__((ext_vector_type(8))) short bhalf8;  // 16B
typedef __attribute__((ext_vector_type(4))) float f4acc;   // MFMA accumulator

__device__ __forceinline__ ushort f2bf(float f) {
  uint u = __float_as_uint(f);
  u += 0x7fffu + ((u >> 16) & 1u);  // RNE
  return (ushort)(u >> 16);
}
__device__ __forceinline__ float bflo(uint u) { return __uint_as_float(u << 16); }
__device__ __forceinline__ float bfhi(uint u) { return __uint_as_float(u & 0xffff0000u); }
__device__ __forceinline__ float bf2f(short s) { return __uint_as_float(((uint)(ushort)s) << 16); }
__device__ __forceinline__ float sigmoidf_fast(float x) { return 1.0f / (1.0f + __expf(-x)); }

// ---------------- weight prep: transpose + bf16 convert ----------------
// blocks [0,384): 6 square mats; blocks 384/385: bias mats padded to 16x128
__global__ __launch_bounds__(256) void k_wprep(const float* __restrict__ Wq,
                                               const float* __restrict__ Wkv,
                                               const float* __restrict__ Wgt_w,
                                               const float* __restrict__ Wgs_w,
                                               const float* __restrict__ Wo,
                                               const float* __restrict__ Wbt,
                                               const float* __restrict__ Wbs,
                                               short* __restrict__ WqT, short* __restrict__ WkT,
                                               short* __restrict__ WvT, short* __restrict__ WgtT,
                                               short* __restrict__ WgsT, short* __restrict__ WoT,
                                               short* __restrict__ WbtT, short* __restrict__ WbsT) {
  if (blockIdx.x >= 384) {
    const float* src = (blockIdx.x == 384) ? Wbt : Wbs;
    short* dst = (blockIdx.x == 384) ? WbtT : WbsT;
    for (int idx = threadIdx.x; idx < 16 * 128; idx += 256) {
      int n = idx >> 7, k = idx & 127;
      dst[idx] = (n < 8) ? (short)f2bf(src[k * 8 + n]) : (short)0;
    }
    return;
  }
  int m = blockIdx.x >> 6;
  int idx = (blockIdx.x & 63) * 256 + threadIdx.x;
  int n = idx >> 7, k = idx & 127;
  const float* src;
  int ld, off;
  short* dst;
  switch (m) {
    case 0: src = Wq;    ld = 128; off = 0;   dst = WqT;  break;
    case 1: src = Wkv;   ld = 256; off = 0;   dst = WkT;  break;
    case 2: src = Wkv;   ld = 256; off = 128; dst = WvT;  break;
    case 3: src = Wgt_w; ld = 128; off = 0;   dst = WgtT; break;
    case 4: src = Wgs_w; ld = 128; off = 0;   dst = WgsT; break;
    default:src = Wo;    ld = 128; off = 0;   dst = WoT;  break;
  }
  dst[n * 128 + k] = (short)f2bf(src[(size_t)k * ld + off + n]);
}

// ---------------- staging helpers ----------------
__device__ __forceinline__ void stage_rows_f32(const float* __restrict__ X, size_t row0,
                                               short (*Xs)[136], int tid) {
  for (int i = tid; i < 64 * 32; i += 256) {
    int r = i >> 5, c4 = (i & 31) * 4;
    float4 v = *reinterpret_cast<const float4*>(X + (row0 + r) * 128 + c4);
    bhalf4 o;
    o[0] = (short)f2bf(v.x); o[1] = (short)f2bf(v.y);
    o[2] = (short)f2bf(v.z); o[3] = (short)f2bf(v.w);
    *reinterpret_cast<bhalf4*>(&Xs[r][c4]) = o;
  }
}
__device__ __forceinline__ void stage_rows_bf16(const short* __restrict__ X, size_t row0,
                                                short (*Xs)[136], int tid) {
  for (int i = tid; i < 64 * 32; i += 256) {
    int r = i >> 5, c4 = (i & 31) * 4;
    *reinterpret_cast<bhalf4*>(&Xs[r][c4]) =
        *reinterpret_cast<const bhalf4*>(X + (row0 + r) * 128 + c4);
  }
}

__device__ __forceinline__ void mfma_pass(const short (*Xs)[136], int wave, int lane,
                                          const short* __restrict__ WT, f4acc acc[8]) {
  const int rl = wave * 16 + (lane & 15);
  const int kg = (lane >> 4) * 8;
  const int nl = lane & 15;
#pragma unroll
  for (int ks = 0; ks < 4; ++ks) {
    bfrag a = *reinterpret_cast<const bfrag*>(&Xs[rl][ks * 32 + kg]);
#pragma unroll
    for (int nf = 0; nf < 8; ++nf) {
      bfrag b = *reinterpret_cast<const bfrag*>(WT + (size_t)(nf * 16 + nl) * 128 + ks * 32 + kg);
      acc[nf] = __builtin_amdgcn_mfma_f32_16x16x32_bf16(a, b, acc[nf], 0, 0, 0);
    }
  }
}

// ---------------- fused projections, coalesced epilogues ----------------
// blocks [0,625): targets -> Qb (pre-scaled), gtb, bt16 (pre-scaled, stride 16)
// blocks [625,1250): sources -> KG rows [K|GV interleaved ×128pairs | bs bf16 ×8 | pad]
__global__ __launch_bounds__(256) void k_proj(const float* __restrict__ Xt,
                                              const float* __restrict__ Xsrc,
                                              const short* __restrict__ WqT,
                                              const short* __restrict__ WgtT,
                                              const short* __restrict__ WkT,
                                              const short* __restrict__ WvT,
                                              const short* __restrict__ WgsT,
                                              const short* __restrict__ WbtT,
                                              const short* __restrict__ WbsT,
                                              const float* __restrict__ Wgt_b,
                                              const float* __restrict__ Wgs_b,
                                              short* __restrict__ Qb, short* __restrict__ gtb,
                                              float* __restrict__ bt16,
                                              short* __restrict__ KG) {
  __shared__ union {
    short Xs[64][136];
    short Stg[4][16][KGS];
  } sh;
  const int tid = threadIdx.x;
  const bool is_src = blockIdx.x >= 625;
  const int cb = is_src ? blockIdx.x - 625 : blockIdx.x;
  const size_t row0 = (size_t)cb * 64;
  stage_rows_f32(is_src ? Xsrc : Xt, row0, sh.Xs, tid);
  __syncthreads();
  const int wr = tid >> 6, lane = tid & 63;
  const int rl = wr * 16 + (lane & 15);
  const int kg = (lane >> 4) * 8;
  const int nl = lane & 15;
  const int cl = lane & 15;
  const int jr0 = (lane >> 4) * 2;  // dummy to keep naming clear (recomputed below)
  const int r4 = (lane >> 4) * 4;   // local row base of C fragment

  if (!is_src) {
    f4acc aQ[8] = {}, aG[8] = {}, aB = {};
#pragma unroll
    for (int ks = 0; ks < 4; ++ks) {
      bfrag a = *reinterpret_cast<const bfrag*>(&sh.Xs[rl][ks * 32 + kg]);
#pragma unroll
      for (int nf = 0; nf < 8; ++nf) {
        const size_t wo = (size_t)(nf * 16 + nl) * 128 + ks * 32 + kg;
        bfrag bq = *reinterpret_cast<const bfrag*>(WqT + wo);
        aQ[nf] = __builtin_amdgcn_mfma_f32_16x16x32_bf16(a, bq, aQ[nf], 0, 0, 0);
        bfrag bg = *reinterpret_cast<const bfrag*>(WgtT + wo);
        aG[nf] = __builtin_amdgcn_mfma_f32_16x16x32_bf16(a, bg, aG[nf], 0, 0, 0);
      }
      bfrag bb = *reinterpret_cast<const bfrag*>(WbtT + (size_t)nl * 128 + ks * 32 + kg);
      aB = __builtin_amdgcn_mfma_f32_16x16x32_bf16(a, bb, aB, 0, 0, 0);
    }
    __syncthreads();  // Xs dead for all waves -> union reuse safe
    // stage Q (cols 0..127) and gt (cols 128..255) into per-wave LDS tile
#pragma unroll
    for (int nf = 0; nf < 8; ++nf)
#pragma unroll
      for (int j = 0; j < 4; ++j) {
        int col = nf * 16 + cl;
        sh.Stg[wr][r4 + j][col] = (short)f2bf(aQ[nf][j] * (0.25f * LOG2E));
        float g = sigmoidf_fast(aG[nf][j] + Wgt_b[col]);
        sh.Stg[wr][r4 + j][128 + col] = (short)f2bf(g);
      }
#pragma unroll
    for (int j = 0; j < 4; ++j)
      bt16[(row0 + wr * 16 + r4 + j) * 16 + cl] = aB[j] * LOG2E;
    // coalesced flush (per-wave tile, DS ops in-order -> no barrier needed)
#pragma unroll
    for (int it = 0; it < 4; ++it) {
      int u = it * 64 + lane;
      int r = u >> 4, o = (u & 15) * 8;
      bhalf8 v = *reinterpret_cast<const bhalf8*>(&sh.Stg[wr][r][o]);
      *reinterpret_cast<bhalf8*>(Qb + (row0 + wr * 16 + r) * 128 + o) = v;
    }
#pragma unroll
    for (int it = 0; it < 4; ++it) {
      int u = it * 64 + lane;
      int r = u >> 4, o = (u & 15) * 8;
      bhalf8 v = *reinterpret_cast<const bhalf8*>(&sh.Stg[wr][r][128 + o]);
      *reinterpret_cast<bhalf8*>(gtb + (row0 + wr * 16 + r) * 128 + o) = v;
    }
  } else {
    f4acc aK[8] = {}, aV[8] = {}, aG[8] = {}, aB = {};
#pragma unroll
    for (int ks = 0; ks < 4; ++ks) {
      bfrag a = *reinterpret_cast<const bfrag*>(&sh.Xs[rl][ks * 32 + kg]);
#pragma unroll
      for (int nf = 0; nf < 8; ++nf) {
        const size_t wo = (size_t)(nf * 16 + nl) * 128 + ks * 32 + kg;
        bfrag bk = *reinterpret_cast<const bfrag*>(WkT + wo);
        aK[nf] = __builtin_amdgcn_mfma_f32_16x16x32_bf16(a, bk, aK[nf], 0, 0, 0);
        bfrag bv = *reinterpret_cast<const bfrag*>(WvT + wo);
        aV[nf] = __builtin_amdgcn_mfma_f32_16x16x32_bf16(a, bv, aV[nf], 0, 0, 0);
        bfrag bg = *reinterpret_cast<const bfrag*>(WgsT + wo);
        aG[nf] = __builtin_amdgcn_mfma_f32_16x16x32_bf16(a, bg, aG[nf], 0, 0, 0);
      }
      bfrag bb = *reinterpret_cast<const bfrag*>(WbsT + (size_t)nl * 128 + ks * 32 + kg);
      aB = __builtin_amdgcn_mfma_f32_16x16x32_bf16(a, bb, aB, 0, 0, 0);
    }
    __syncthreads();  // union reuse safe
    // stage interleaved K/GV (+ bs bf16 at col 256) into per-wave LDS tile
#pragma unroll
    for (int nf = 0; nf < 8; ++nf)
#pragma unroll
      for (int j = 0; j < 4; ++j) {
        int col = nf * 16 + cl;
        int slot = (col >> 1) * 4 + (col & 1);
        float g = sigmoidf_fast(aG[nf][j] + Wgs_b[col]);
        sh.Stg[wr][r4 + j][slot] = (short)f2bf(aK[nf][j]);
        sh.Stg[wr][r4 + j][slot + 2] = (short)f2bf(g * aV[nf][j]);
      }
#pragma unroll
    for (int j = 0; j < 4; ++j)
      sh.Stg[wr][r4 + j][256 + cl] = (short)f2bf(aB[j] * LOG2E);  // cols 8..15 are zeros
    // coalesced flush: 16 rows x 34 16B-units = 544 units
    for (int u = lane; u < 544; u += 64) {
      int r = u / 34, o = (u - r * 34) * 8;
      bhalf8 v = *reinterpret_cast<const bhalf8*>(&sh.Stg[wr][r][o]);
      *reinterpret_cast<bhalf8*>(KG + (row0 + wr * 16 + r) * KGS + o) = v;
    }
  }
}

// ---------------- CSR build ----------------
__global__ void k_hist(const int* __restrict__ inc_tgt, int* __restrict__ cnt) {
  int e = blockIdx.x * 256 + threadIdx.x;
  if (e < NEDGE) atomicAdd(&cnt[inc_tgt[e]], 1);
}

__global__ __launch_bounds__(1024) void k_scan(const int* __restrict__ cnt,
                                               int* __restrict__ rowstart) {
  __shared__ int wsum[16];
  const int tid = threadIdx.x;
  const int base = tid * 40;  // 1024*40 >= 40000
  int pref[40];
  int s = 0;
#pragma unroll
  for (int j = 0; j < 40; ++j) {
    int idx = base + j;
    int c = (idx < NTGT) ? cnt[idx] : 0;
    pref[j] = s;
    s += c;
  }
  const int lane = tid & 63, w = tid >> 6;
  int incl = s;
#pragma unroll
  for (int d = 1; d < 64; d <<= 1) {
    int t = __shfl_up(incl, d);
    if (lane >= d) incl += t;
  }
  if (lane == 63) wsum[w] = incl;
  __syncthreads();
  if (tid < 16) {
    int v = wsum[tid];
#pragma unroll
    for (int d = 1; d < 16; d <<= 1) {
      int t = __shfl_up(v, d);
      if (tid >= d) v += t;
    }
    wsum[tid] = v;
  }
  __syncthreads();
  const int tbase = incl - s + (w ? wsum[w - 1] : 0);
#pragma unroll
  for (int j = 0; j < 40; ++j) {
    int idx = base + j;
    if (idx < NTGT) rowstart[idx] = tbase + pref[j];
  }
  if (tid == 1023) rowstart[NTGT] = wsum[15];
}

__global__ void k_scatter(const int* __restrict__ inc_tgt, const int* __restrict__ inc_src,
                          const int* __restrict__ rowstart, int* __restrict__ cur,
                          int* __restrict__ elist) {
  int e = blockIdx.x * 256 + threadIdx.x;
  if (e < NEDGE) {
    int t = inc_tgt[e];
    int pos = atomicAdd(&cur[t], 1);
    elist[rowstart[t] + pos] = inc_src[e];
  }
}

// ---------------- per-target softmax attention (exp2 domain, no max) ----------------
__global__ __launch_bounds__(256) void k_attn(const uint* __restrict__ Qp,
                                              const uint2* __restrict__ KGp,
                                              const float* __restrict__ bt16,
                                              const uint* __restrict__ gtp,
                                              const int* __restrict__ rowstart,
                                              const int* __restrict__ elist,
                                              uint* __restrict__ tmpp) {
  const int wave = threadIdx.x >> 6;
  const int lane = threadIdx.x & 63;
  const int t = blockIdx.x * 4 + wave;  // 10000*4 == 40000
  const int h = lane >> 3;
  const short* KGs = (const short*)KGp;

  uint qu = Qp[(size_t)t * 64 + lane];      // pre-scaled by 0.25*log2e
  float qx = bflo(qu), qy = bfhi(qu);
  const float bt2 = bt16[(size_t)t * 16 + h];  // pre-scaled by log2e
  const int rs = rowstart[t], re = rowstart[t + 1];

  float ssum = 0.f, a0 = 0.f, a1 = 0.f;
  int i = rs;
  for (; i + 4 <= re; i += 4) {
    int s0 = elist[i], s1 = elist[i + 1], s2 = elist[i + 2], s3 = elist[i + 3];
    uint2 k0 = KGp[(size_t)s0 * 68 + lane];
    uint2 k1 = KGp[(size_t)s1 * 68 + lane];
    uint2 k2 = KGp[(size_t)s2 * 68 + lane];
    uint2 k3 = KGp[(size_t)s3 * 68 + lane];
    float b0 = bf2f(KGs[(size_t)s0 * KGS + 256 + h]);
    float b1 = bf2f(KGs[(size_t)s1 * KGS + 256 + h]);
    float b2 = bf2f(KGs[(size_t)s2 * KGS + 256 + h]);
    float b3 = bf2f(KGs[(size_t)s3 * KGS + 256 + h]);
    float d0 = qx * bflo(k0.x) + qy * bfhi(k0.x);
    float d1 = qx * bflo(k1.x) + qy * bfhi(k1.x);
    float d2 = qx * bflo(k2.x) + qy * bfhi(k2.x);
    float d3 = qx * bflo(k3.x) + qy * bfhi(k3.x);
    d0 += __shfl_xor(d0, 1); d1 += __shfl_xor(d1, 1); d2 += __shfl_xor(d2, 1); d3 += __shfl_xor(d3, 1);
    d0 += __shfl_xor(d0, 2); d1 += __shfl_xor(d1, 2); d2 += __shfl_xor(d2, 2); d3 += __shfl_xor(d3, 2);
    d0 += __shfl_xor(d0, 4); d1 += __shfl_xor(d1, 4); d2 += __shfl_xor(d2, 4); d3 += __shfl_xor(d3, 4);
    float e0 = __builtin_amdgcn_exp2f(d0 + bt2 + b0);
    float e1 = __builtin_amdgcn_exp2f(d1 + bt2 + b1);
    float e2 = __builtin_amdgcn_exp2f(d2 + bt2 + b2);
    float e3 = __builtin_amdgcn_exp2f(d3 + bt2 + b3);
    ssum += (e0 + e1) + (e2 + e3);
    a0 = fmaf(e0, bflo(k0.y), fmaf(e1, bflo(k1.y), fmaf(e2, bflo(k2.y), fmaf(e3, bflo(k3.y), a0))));
    a1 = fmaf(e0, bfhi(k0.y), fmaf(e1, bfhi(k1.y), fmaf(e2, bfhi(k2.y), fmaf(e3, bfhi(k3.y), a1))));
  }
  for (; i < re; ++i) {
    int s0 = elist[i];
    uint2 k0 = KGp[(size_t)s0 * 68 + lane];
    float b0 = bf2f(KGs[(size_t)s0 * KGS + 256 + h]);
    float d0 = qx * bflo(k0.x) + qy * bfhi(k0.x);
    d0 += __shfl_xor(d0, 1);
    d0 += __shfl_xor(d0, 2);
    d0 += __shfl_xor(d0, 4);
    float e0 = __builtin_amdgcn_exp2f(d0 + bt2 + b0);
    ssum += e0;
    a0 = fmaf(e0, bflo(k0.y), a0);
    a1 = fmaf(e0, bfhi(k0.y), a1);
  }
  float inv = 1.f / (ssum + 1e-12f);
  uint g2 = gtp[(size_t)t * 64 + lane];
  float ox = bflo(g2) * a0 * inv;
  float oy = bfhi(g2) * a1 * inv;
  tmpp[(size_t)t * 64 + lane] = ((uint)f2bf(ox)) | (((uint)f2bf(oy)) << 16);
}

// ---------------- final GEMM: out = tmp @ Wo (fp32 out) ----------------
__global__ __launch_bounds__(256) void k_out(const short* __restrict__ tmpb,
                                             const short* __restrict__ WoT,
                                             float* __restrict__ out) {
  __shared__ short Xs[64][136];
  const int tid = threadIdx.x;
  const size_t row0 = (size_t)blockIdx.x * 64;
  stage_rows_bf16(tmpb, row0, Xs, tid);
  __syncthreads();
  const int wave = tid >> 6, lane = tid & 63;
  const int rbase = (int)row0 + wave * 16 + ((lane >> 4) << 2);
  const int cl = lane & 15;
  f4acc acc[8] = {};
  mfma_pass(Xs, wave, lane, WoT, acc);
#pragma unroll
  for (int nf = 0; nf < 8; ++nf)
#pragma unroll
    for (int j = 0; j < 4; ++j)
      out[(size_t)(rbase + j) * 128 + nf * 16 + cl] = acc[nf][j];
}

extern "C" void kernel_launch(void* const* d_in, const int* in_sizes, int n_in,
                              void* d_out, int out_size, void* d_ws, size_t ws_size,
                              hipStream_t stream) {
  const float* X_tgt = (const float*)d_in[0];
  const float* X_src = (const float*)d_in[1];
  const int* inc_tgt = (const int*)d_in[2];
  const int* inc_src = (const int*)d_in[3];
  const float* Wq    = (const float*)d_in[5];
  const float* Wkv   = (const float*)d_in[6];
  const float* Wbt   = (const float*)d_in[7];
  const float* Wbs   = (const float*)d_in[8];
  const float* Wgt_w = (const float*)d_in[9];
  const float* Wgt_b = (const float*)d_in[10];
  const float* Wgs_w = (const float*)d_in[11];
  const float* Wgs_b = (const float*)d_in[12];
  const float* Wo    = (const float*)d_in[13];
  float* out = (float*)d_out;

  char* ws = (char*)d_ws;
  short* Qb   = (short*)ws; ws += (size_t)NTGT * 128 * 2;
  short* KG   = (short*)ws; ws += (size_t)NSRC * KGS * 2;
  short* gtb  = (short*)ws; ws += (size_t)NTGT * 128 * 2;
  short* tmpb = (short*)ws; ws += (size_t)NTGT * 128 * 2;
  float* bt16 = (float*)ws; ws += (size_t)NTGT * 16 * 4;
  int* rowstart = (int*)ws; ws += (size_t)(NTGT + 4) * 4;
  int* cnt  = (int*)ws; ws += (size_t)NTGT * 4;  // cnt & cur adjacent: one memset
  int* cur  = (int*)ws; ws += (size_t)NTGT * 4;
  int* elist = (int*)ws; ws += (size_t)NEDGE * 4;
  short* WqT  = (short*)ws; ws += 128 * 128 * 2;
  short* WkT  = (short*)ws; ws += 128 * 128 * 2;
  short* WvT  = (short*)ws; ws += 128 * 128 * 2;
  short* WgtT = (short*)ws; ws += 128 * 128 * 2;
  short* WgsT = (short*)ws; ws += 128 * 128 * 2;
  short* WoT  = (short*)ws; ws += 128 * 128 * 2;
  short* WbtT = (short*)ws; ws += 16 * 128 * 2;
  short* WbsT = (short*)ws; ws += 16 * 128 * 2;

  hipMemsetAsync(cnt, 0, (size_t)2 * NTGT * 4, stream);

  k_wprep<<<386, 256, 0, stream>>>(Wq, Wkv, Wgt_w, Wgs_w, Wo, Wbt, Wbs,
                                   WqT, WkT, WvT, WgtT, WgsT, WoT, WbtT, WbsT);
  k_hist<<<NEDGE / 256, 256, 0, stream>>>(inc_tgt, cnt);
  k_proj<<<1250, 256, 0, stream>>>(X_tgt, X_src, WqT, WgtT, WkT, WvT, WgsT,
                                   WbtT, WbsT, Wgt_b, Wgs_b, Qb, gtb, bt16, KG);
  k_scan<<<1, 1024, 0, stream>>>(cnt, rowstart);
  k_scatter<<<NEDGE / 256, 256, 0, stream>>>(inc_tgt, inc_src, rowstart, cur, elist);
  k_attn<<<NTGT / 4, 256, 0, stream>>>((const uint*)Qb, (const uint2*)KG, bt16,
                                       (const uint*)gtb, rowstart, elist, (uint*)tmpb);
  k_out<<<NTGT / 64, 256, 0, stream>>>(tmpb, WoT, out);
}

// Round 5
// 221.851 us; speedup vs baseline: 1.2159x; 1.1767x over previous
//
#include <hip/hip_runtime.h>
#include <math.h>

#define NTGT 40000
#define NSRC 40000
#define NEDGE 640000
#define LOG2E 1.44269504088896f
#define KGS 272  // shorts per KG row: 256 K/GV interleaved + 8 bs(bf16) + 8 pad

typedef __attribute__((ext_vector_type(8))) short bfrag;   // 8 bf16 (4 VGPRs)
typedef __attribute__((ext_vector_type(4))) short bhalf4;  // 8B
typedef __attribute__((ext_vector_type(8))) short bhalf8;  // 16B
typedef __attribute__((ext_vector_type(4))) float f4acc;   // MFMA accumulator

__device__ __forceinline__ ushort f2bf(float f) {
  uint u = __float_as_uint(f);
  u += 0x7fffu + ((u >> 16) & 1u);  // RNE
  return (ushort)(u >> 16);
}
__device__ __forceinline__ float bflo(uint u) { return __uint_as_float(u << 16); }
__device__ __forceinline__ float bfhi(uint u) { return __uint_as_float(u & 0xffff0000u); }
__device__ __forceinline__ float bf2f(short s) { return __uint_as_float(((uint)(ushort)s) << 16); }
__device__ __forceinline__ float sigmoidf_fast(float x) { return 1.0f / (1.0f + __expf(-x)); }

// ---------------- prep: weight transpose/convert + edge histogram ----------------
// blocks [0,384): 6 square mats; 384/385: bias mats padded to 16x128; [386,2886): histogram
__global__ __launch_bounds__(256) void k_prep(const float* __restrict__ Wq,
                                              const float* __restrict__ Wkv,
                                              const float* __restrict__ Wgt_w,
                                              const float* __restrict__ Wgs_w,
                                              const float* __restrict__ Wo,
                                              const float* __restrict__ Wbt,
                                              const float* __restrict__ Wbs,
                                              const int* __restrict__ inc_tgt,
                                              int* __restrict__ cnt,
                                              short* __restrict__ WqT, short* __restrict__ WkT,
                                              short* __restrict__ WvT, short* __restrict__ WgtT,
                                              short* __restrict__ WgsT, short* __restrict__ WoT,
                                              short* __restrict__ WbtT, short* __restrict__ WbsT) {
  const int b = blockIdx.x;
  if (b >= 386) {
    int e = (b - 386) * 256 + threadIdx.x;  // 2500*256 == NEDGE exact
    atomicAdd(&cnt[inc_tgt[e]], 1);
    return;
  }
  if (b >= 384) {
    const float* src = (b == 384) ? Wbt : Wbs;
    short* dst = (b == 384) ? WbtT : WbsT;
    for (int idx = threadIdx.x; idx < 16 * 128; idx += 256) {
      int n = idx >> 7, k = idx & 127;
      dst[idx] = (n < 8) ? (short)f2bf(src[k * 8 + n]) : (short)0;
    }
    return;
  }
  int m = b >> 6;
  int idx = (b & 63) * 256 + threadIdx.x;
  int n = idx >> 7, k = idx & 127;
  const float* src;
  int ld, off;
  short* dst;
  switch (m) {
    case 0: src = Wq;    ld = 128; off = 0;   dst = WqT;  break;
    case 1: src = Wkv;   ld = 256; off = 0;   dst = WkT;  break;
    case 2: src = Wkv;   ld = 256; off = 128; dst = WvT;  break;
    case 3: src = Wgt_w; ld = 128; off = 0;   dst = WgtT; break;
    case 4: src = Wgs_w; ld = 128; off = 0;   dst = WgsT; break;
    default:src = Wo;    ld = 128; off = 0;   dst = WoT;  break;
  }
  dst[n * 128 + k] = (short)f2bf(src[(size_t)k * ld + off + n]);
}

// ---------------- staging helpers ----------------
__device__ __forceinline__ void stage_rows_f32(const float* __restrict__ X, size_t row0,
                                               short (*Xs)[136], int tid) {
  for (int i = tid; i < 64 * 32; i += 256) {
    int r = i >> 5, c4 = (i & 31) * 4;
    float4 v = *reinterpret_cast<const float4*>(X + (row0 + r) * 128 + c4);
    bhalf4 o;
    o[0] = (short)f2bf(v.x); o[1] = (short)f2bf(v.y);
    o[2] = (short)f2bf(v.z); o[3] = (short)f2bf(v.w);
    *reinterpret_cast<bhalf4*>(&Xs[r][c4]) = o;
  }
}
__device__ __forceinline__ void stage_rows_bf16(const short* __restrict__ X, size_t row0,
                                                short (*Xs)[136], int tid) {
  for (int i = tid; i < 64 * 32; i += 256) {
    int r = i >> 5, c4 = (i & 31) * 4;
    *reinterpret_cast<bhalf4*>(&Xs[r][c4]) =
        *reinterpret_cast<const bhalf4*>(X + (row0 + r) * 128 + c4);
  }
}

#define MFMA16(a, b, c) __builtin_amdgcn_mfma_f32_16x16x32_bf16(a, b, c, 0, 0, 0)

// ---------------- fused projections: wave = 64-row x 16-col strip ----------------
// blocks [0,625): targets -> Qb (pre-scaled), gtb, bt16 (pre-scaled, stride 16)
// blocks [625,1250): sources -> KG rows [K|GV interleaved x128pairs | bs bf16 x8 | pad]
// Each wave: cols [cit*64 + w*16, +16), all 64 rows. One B-load feeds 4 MFMAs.
__global__ __launch_bounds__(256) void k_proj(const float* __restrict__ Xt,
                                              const float* __restrict__ Xsrc,
                                              const short* __restrict__ WqT,
                                              const short* __restrict__ WgtT,
                                              const short* __restrict__ WkT,
                                              const short* __restrict__ WvT,
                                              const short* __restrict__ WgsT,
                                              const short* __restrict__ WbtT,
                                              const short* __restrict__ WbsT,
                                              const float* __restrict__ Wgt_b,
                                              const float* __restrict__ Wgs_b,
                                              short* __restrict__ Qb, short* __restrict__ gtb,
                                              float* __restrict__ bt16,
                                              short* __restrict__ KG) {
  __shared__ union {
    short Xs[64][136];
    short Stg[64][KGS];
  } sh;
  const int tid = threadIdx.x;
  const bool is_src = blockIdx.x >= 625;
  const int cb = is_src ? blockIdx.x - 625 : blockIdx.x;
  const size_t row0 = (size_t)cb * 64;
  stage_rows_f32(is_src ? Xsrc : Xt, row0, sh.Xs, tid);
  __syncthreads();
  const int w = tid >> 6, lane = tid & 63;
  const int nl = lane & 15;        // A-row / B-col / C-col within fragment
  const int kg = (lane >> 4) * 8;  // k offset within fragment
  const int r4 = (lane >> 4) * 4;  // C-row offset within row-fragment

  if (!is_src) {
    f4acc aQ[2][4] = {}, aG[2][4] = {}, aB[4] = {};
#pragma unroll
    for (int cit = 0; cit < 2; ++cit) {
      const int c0 = cit * 64 + w * 16;
#pragma unroll
      for (int ks = 0; ks < 4; ++ks) {
        const int ko = ks * 32 + kg;
        bfrag a0 = *reinterpret_cast<const bfrag*>(&sh.Xs[nl][ko]);
        bfrag a1 = *reinterpret_cast<const bfrag*>(&sh.Xs[16 + nl][ko]);
        bfrag a2 = *reinterpret_cast<const bfrag*>(&sh.Xs[32 + nl][ko]);
        bfrag a3 = *reinterpret_cast<const bfrag*>(&sh.Xs[48 + nl][ko]);
        const size_t wo = (size_t)(c0 + nl) * 128 + ko;
        bfrag bq = *reinterpret_cast<const bfrag*>(WqT + wo);
        bfrag bg = *reinterpret_cast<const bfrag*>(WgtT + wo);
        aQ[cit][0] = MFMA16(a0, bq, aQ[cit][0]);
        aQ[cit][1] = MFMA16(a1, bq, aQ[cit][1]);
        aQ[cit][2] = MFMA16(a2, bq, aQ[cit][2]);
        aQ[cit][3] = MFMA16(a3, bq, aQ[cit][3]);
        aG[cit][0] = MFMA16(a0, bg, aG[cit][0]);
        aG[cit][1] = MFMA16(a1, bg, aG[cit][1]);
        aG[cit][2] = MFMA16(a2, bg, aG[cit][2]);
        aG[cit][3] = MFMA16(a3, bg, aG[cit][3]);
        if (cit == 0 && w == 0) {
          bfrag bb = *reinterpret_cast<const bfrag*>(WbtT + (size_t)nl * 128 + ko);
          aB[0] = MFMA16(a0, bb, aB[0]);
          aB[1] = MFMA16(a1, bb, aB[1]);
          aB[2] = MFMA16(a2, bb, aB[2]);
          aB[3] = MFMA16(a3, bb, aB[3]);
        }
      }
    }
    __syncthreads();  // Xs dead -> union reuse safe
#pragma unroll
    for (int cit = 0; cit < 2; ++cit) {
      const int c = cit * 64 + w * 16 + nl;
      const float gb = Wgt_b[c];
#pragma unroll
      for (int rf = 0; rf < 4; ++rf)
#pragma unroll
        for (int j = 0; j < 4; ++j) {
          int r = rf * 16 + r4 + j;
          sh.Stg[r][c] = (short)f2bf(aQ[cit][rf][j] * (0.25f * LOG2E));
          sh.Stg[r][128 + c] = (short)f2bf(sigmoidf_fast(aG[cit][rf][j] + gb));
        }
    }
    if (w == 0) {
#pragma unroll
      for (int rf = 0; rf < 4; ++rf)
#pragma unroll
        for (int j = 0; j < 4; ++j)
          bt16[(row0 + rf * 16 + r4 + j) * 16 + nl] = aB[rf][j] * LOG2E;
    }
    __syncthreads();
    for (int u = tid; u < 1024; u += 256) {
      int r = u >> 4, o = (u & 15) * 8;
      *reinterpret_cast<bhalf8*>(Qb + (row0 + r) * 128 + o) =
          *reinterpret_cast<const bhalf8*>(&sh.Stg[r][o]);
      *reinterpret_cast<bhalf8*>(gtb + (row0 + r) * 128 + o) =
          *reinterpret_cast<const bhalf8*>(&sh.Stg[r][128 + o]);
    }
  } else {
    f4acc aK[2][4] = {}, aV[2][4] = {}, aG[2][4] = {}, aB[4] = {};
#pragma unroll
    for (int cit = 0; cit < 2; ++cit) {
      const int c0 = cit * 64 + w * 16;
#pragma unroll
      for (int ks = 0; ks < 4; ++ks) {
        const int ko = ks * 32 + kg;
        bfrag a0 = *reinterpret_cast<const bfrag*>(&sh.Xs[nl][ko]);
        bfrag a1 = *reinterpret_cast<const bfrag*>(&sh.Xs[16 + nl][ko]);
        bfrag a2 = *reinterpret_cast<const bfrag*>(&sh.Xs[32 + nl][ko]);
        bfrag a3 = *reinterpret_cast<const bfrag*>(&sh.Xs[48 + nl][ko]);
        const size_t wo = (size_t)(c0 + nl) * 128 + ko;
        bfrag bk = *reinterpret_cast<const bfrag*>(WkT + wo);
        bfrag bv = *reinterpret_cast<const bfrag*>(WvT + wo);
        bfrag bg = *reinterpret_cast<const bfrag*>(WgsT + wo);
        aK[cit][0] = MFMA16(a0, bk, aK[cit][0]);
        aK[cit][1] = MFMA16(a1, bk, aK[cit][1]);
        aK[cit][2] = MFMA16(a2, bk, aK[cit][2]);
        aK[cit][3] = MFMA16(a3, bk, aK[cit][3]);
        aV[cit][0] = MFMA16(a0, bv, aV[cit][0]);
        aV[cit][1] = MFMA16(a1, bv, aV[cit][1]);
        aV[cit][2] = MFMA16(a2, bv, aV[cit][2]);
        aV[cit][3] = MFMA16(a3, bv, aV[cit][3]);
        aG[cit][0] = MFMA16(a0, bg, aG[cit][0]);
        aG[cit][1] = MFMA16(a1, bg, aG[cit][1]);
        aG[cit][2] = MFMA16(a2, bg, aG[cit][2]);
        aG[cit][3] = MFMA16(a3, bg, aG[cit][3]);
        if (cit == 0 && w == 0) {
          bfrag bb = *reinterpret_cast<const bfrag*>(WbsT + (size_t)nl * 128 + ko);
          aB[0] = MFMA16(a0, bb, aB[0]);
          aB[1] = MFMA16(a1, bb, aB[1]);
          aB[2] = MFMA16(a2, bb, aB[2]);
          aB[3] = MFMA16(a3, bb, aB[3]);
        }
      }
    }
    __syncthreads();  // union reuse safe
#pragma unroll
    for (int cit = 0; cit < 2; ++cit) {
      const int c = cit * 64 + w * 16 + nl;
      const int slot = (c >> 1) * 4 + (c & 1);
      const float gb = Wgs_b[c];
#pragma unroll
      for (int rf = 0; rf < 4; ++rf)
#pragma unroll
        for (int j = 0; j < 4; ++j) {
          int r = rf * 16 + r4 + j;
          float g = sigmoidf_fast(aG[cit][rf][j] + gb);
          sh.Stg[r][slot] = (short)f2bf(aK[cit][rf][j]);
          sh.Stg[r][slot + 2] = (short)f2bf(g * aV[cit][rf][j]);
        }
    }
    if (w == 0) {
#pragma unroll
      for (int rf = 0; rf < 4; ++rf)
#pragma unroll
        for (int j = 0; j < 4; ++j)
          sh.Stg[rf * 16 + r4 + j][256 + nl] = (short)f2bf(aB[rf][j] * LOG2E);  // cols 8..15 zero
    }
    __syncthreads();
    for (int u = tid; u < 2176; u += 256) {
      int r = u / 34, o = (u - r * 34) * 8;
      *reinterpret_cast<bhalf8*>(KG + (row0 + r) * KGS + o) =
          *reinterpret_cast<const bhalf8*>(&sh.Stg[r][o]);
    }
  }
}

// ---------------- CSR scan + scatter ----------------
__global__ __launch_bounds__(1024) void k_scan(const int* __restrict__ cnt,
                                               int* __restrict__ rowstart) {
  __shared__ int wsum[16];
  const int tid = threadIdx.x;
  const int base = tid * 40;  // 1024*40 >= 40000
  int pref[40];
  int s = 0;
#pragma unroll
  for (int j = 0; j < 40; ++j) {
    int idx = base + j;
    int c = (idx < NTGT) ? cnt[idx] : 0;
    pref[j] = s;
    s += c;
  }
  const int lane = tid & 63, w = tid >> 6;
  int incl = s;
#pragma unroll
  for (int d = 1; d < 64; d <<= 1) {
    int t = __shfl_up(incl, d);
    if (lane >= d) incl += t;
  }
  if (lane == 63) wsum[w] = incl;
  __syncthreads();
  if (tid < 16) {
    int v = wsum[tid];
#pragma unroll
    for (int d = 1; d < 16; d <<= 1) {
      int t = __shfl_up(v, d);
      if (tid >= d) v += t;
    }
    wsum[tid] = v;
  }
  __syncthreads();
  const int tbase = incl - s + (w ? wsum[w - 1] : 0);
#pragma unroll
  for (int j = 0; j < 40; ++j) {
    int idx = base + j;
    if (idx < NTGT) rowstart[idx] = tbase + pref[j];
  }
  if (tid == 1023) rowstart[NTGT] = wsum[15];
}

__global__ void k_scatter(const int* __restrict__ inc_tgt, const int* __restrict__ inc_src,
                          const int* __restrict__ rowstart, int* __restrict__ cur,
                          int* __restrict__ elist) {
  int e = blockIdx.x * 256 + threadIdx.x;
  if (e < NEDGE) {
    int t = inc_tgt[e];
    int pos = atomicAdd(&cur[t], 1);
    elist[rowstart[t] + pos] = inc_src[e];
  }
}

// ---------------- per-target softmax attention (exp2 domain, no max) ----------------
__global__ __launch_bounds__(256) void k_attn(const uint* __restrict__ Qp,
                                              const uint2* __restrict__ KGp,
                                              const float* __restrict__ bt16,
                                              const uint* __restrict__ gtp,
                                              const int* __restrict__ rowstart,
                                              const int* __restrict__ elist,
                                              uint* __restrict__ tmpp) {
  const int wave = threadIdx.x >> 6;
  const int lane = threadIdx.x & 63;
  const int t = blockIdx.x * 4 + wave;  // 10000*4 == 40000
  const int h = lane >> 3;
  const short* KGs = (const short*)KGp;

  uint qu = Qp[(size_t)t * 64 + lane];         // pre-scaled by 0.25*log2e
  float qx = bflo(qu), qy = bfhi(qu);
  const float bt2 = bt16[(size_t)t * 16 + h];  // pre-scaled by log2e
  const int rs = rowstart[t], re = rowstart[t + 1];

  float ssum = 0.f, a0 = 0.f, a1 = 0.f;
  int i = rs;
  for (; i + 8 <= re; i += 8) {
    int sv[8];
    uint2 kk[8];
    float bb[8], dd[8];
#pragma unroll
    for (int u = 0; u < 8; ++u) sv[u] = elist[i + u];
#pragma unroll
    for (int u = 0; u < 8; ++u) {
      kk[u] = KGp[(size_t)sv[u] * 68 + lane];
      bb[u] = bf2f(KGs[(size_t)sv[u] * KGS + 256 + h]);
    }
#pragma unroll
    for (int u = 0; u < 8; ++u) dd[u] = qx * bflo(kk[u].x) + qy * bfhi(kk[u].x);
#pragma unroll
    for (int u = 0; u < 8; ++u) dd[u] += __shfl_xor(dd[u], 1);
#pragma unroll
    for (int u = 0; u < 8; ++u) dd[u] += __shfl_xor(dd[u], 2);
#pragma unroll
    for (int u = 0; u < 8; ++u) dd[u] += __shfl_xor(dd[u], 4);
#pragma unroll
    for (int u = 0; u < 8; ++u) {
      float e0 = __builtin_amdgcn_exp2f(dd[u] + bt2 + bb[u]);
      ssum += e0;
      a0 = fmaf(e0, bflo(kk[u].y), a0);
      a1 = fmaf(e0, bfhi(kk[u].y), a1);
    }
  }
  for (; i < re; ++i) {
    int s0 = elist[i];
    uint2 k0 = KGp[(size_t)s0 * 68 + lane];
    float b0 = bf2f(KGs[(size_t)s0 * KGS + 256 + h]);
    float d0 = qx * bflo(k0.x) + qy * bfhi(k0.x);
    d0 += __shfl_xor(d0, 1);
    d0 += __shfl_xor(d0, 2);
    d0 += __shfl_xor(d0, 4);
    float e0 = __builtin_amdgcn_exp2f(d0 + bt2 + b0);
    ssum += e0;
    a0 = fmaf(e0, bflo(k0.y), a0);
    a1 = fmaf(e0, bfhi(k0.y), a1);
  }
  float inv = 1.f / (ssum + 1e-12f);
  uint g2 = gtp[(size_t)t * 64 + lane];
  float ox = bflo(g2) * a0 * inv;
  float oy = bfhi(g2) * a1 * inv;
  tmpp[(size_t)t * 64 + lane] = ((uint)f2bf(ox)) | (((uint)f2bf(oy)) << 16);
}

// ---------------- final GEMM: out = tmp @ Wo (fp32 out) ----------------
__device__ __forceinline__ void mfma_pass(const short (*Xs)[136], int wave, int lane,
                                          const short* __restrict__ WT, f4acc acc[8]) {
  const int rl = wave * 16 + (lane & 15);
  const int kg = (lane >> 4) * 8;
  const int nl = lane & 15;
#pragma unroll
  for (int ks = 0; ks < 4; ++ks) {
    bfrag a = *reinterpret_cast<const bfrag*>(&Xs[rl][ks * 32 + kg]);
#pragma unroll
    for (int nf = 0; nf < 8; ++nf) {
      bfrag b = *reinterpret_cast<const bfrag*>(WT + (size_t)(nf * 16 + nl) * 128 + ks * 32 + kg);
      acc[nf] = MFMA16(a, b, acc[nf]);
    }
  }
}

__global__ __launch_bounds__(256) void k_out(const short* __restrict__ tmpb,
                                             const short* __restrict__ WoT,
                                             float* __restrict__ out) {
  __shared__ short Xs[64][136];
  const int tid = threadIdx.x;
  const size_t row0 = (size_t)blockIdx.x * 64;
  stage_rows_bf16(tmpb, row0, Xs, tid);
  __syncthreads();
  const int wave = tid >> 6, lane = tid & 63;
  const int rbase = (int)row0 + wave * 16 + ((lane >> 4) << 2);
  const int cl = lane & 15;
  f4acc acc[8] = {};
  mfma_pass(Xs, wave, lane, WoT, acc);
#pragma unroll
  for (int nf = 0; nf < 8; ++nf)
#pragma unroll
    for (int j = 0; j < 4; ++j)
      out[(size_t)(rbase + j) * 128 + nf * 16 + cl] = acc[nf][j];
}

extern "C" void kernel_launch(void* const* d_in, const int* in_sizes, int n_in,
                              void* d_out, int out_size, void* d_ws, size_t ws_size,
                              hipStream_t stream) {
  const float* X_tgt = (const float*)d_in[0];
  const float* X_src = (const float*)d_in[1];
  const int* inc_tgt = (const int*)d_in[2];
  const int* inc_src = (const int*)d_in[3];
  const float* Wq    = (const float*)d_in[5];
  const float* Wkv   = (const float*)d_in[6];
  const float* Wbt   = (const float*)d_in[7];
  const float* Wbs   = (const float*)d_in[8];
  const float* Wgt_w = (const float*)d_in[9];
  const float* Wgt_b = (const float*)d_in[10];
  const float* Wgs_w = (const float*)d_in[11];
  const float* Wgs_b = (const float*)d_in[12];
  const float* Wo    = (const float*)d_in[13];
  float* out = (float*)d_out;

  char* ws = (char*)d_ws;
  short* Qb   = (short*)ws; ws += (size_t)NTGT * 128 * 2;
  short* KG   = (short*)ws; ws += (size_t)NSRC * KGS * 2;
  short* gtb  = (short*)ws; ws += (size_t)NTGT * 128 * 2;
  short* tmpb = (short*)ws; ws += (size_t)NTGT * 128 * 2;
  float* bt16 = (float*)ws; ws += (size_t)NTGT * 16 * 4;
  int* rowstart = (int*)ws; ws += (size_t)(NTGT + 4) * 4;
  int* cnt  = (int*)ws; ws += (size_t)NTGT * 4;  // cnt & cur adjacent: one memset
  int* cur  = (int*)ws; ws += (size_t)NTGT * 4;
  int* elist = (int*)ws; ws += (size_t)NEDGE * 4;
  short* WqT  = (short*)ws; ws += 128 * 128 * 2;
  short* WkT  = (short*)ws; ws += 128 * 128 * 2;
  short* WvT  = (short*)ws; ws += 128 * 128 * 2;
  short* WgtT = (short*)ws; ws += 128 * 128 * 2;
  short* WgsT = (short*)ws; ws += 128 * 128 * 2;
  short* WoT  = (short*)ws; ws += 128 * 128 * 2;
  short* WbtT = (short*)ws; ws += 16 * 128 * 2;
  short* WbsT = (short*)ws; ws += 16 * 128 * 2;

  hipMemsetAsync(cnt, 0, (size_t)2 * NTGT * 4, stream);

  k_prep<<<2886, 256, 0, stream>>>(Wq, Wkv, Wgt_w, Wgs_w, Wo, Wbt, Wbs, inc_tgt, cnt,
                                   WqT, WkT, WvT, WgtT, WgsT, WoT, WbtT, WbsT);
  k_proj<<<1250, 256, 0, stream>>>(X_tgt, X_src, WqT, WgtT, WkT, WvT, WgsT,
                                   WbtT, WbsT, Wgt_b, Wgs_b, Qb, gtb, bt16, KG);
  k_scan<<<1, 1024, 0, stream>>>(cnt, rowstart);
  k_scatter<<<NEDGE / 256, 256, 0, stream>>>(inc_tgt, inc_src, rowstart, cur, elist);
  k_attn<<<NTGT / 4, 256, 0, stream>>>((const uint*)Qb, (const uint2*)KG, bt16,
                                       (const uint*)gtb, rowstart, elist, (uint*)tmpb);
  k_out<<<NTGT / 64, 256, 0, stream>>>(tmpb, WoT, out);
}